// Round 7
// baseline (123.638 us; speedup 1.0000x reference)
//
#include <hip/hip_runtime.h>

#define OC 1024
#define ICN 1024
#define KK 9
#define CH (ICN * KK)       // 9216 floats per channel
#define CH4 (CH / 4)        // 2304 float4
#define NROWS (OC * ICN)    // 1048576 rows of 9
#define KMB 2048            // kmax blocks
#define RPB 256             // rows per bulk block
#define BULKB (NROWS / RPB) // 4096 bulk blocks
#define BF (RPB * KK)       // 2304 floats per bulk block
#define BF4 (BF / 4)        // 576 float4

// ws layout: part[2048] floats @0; res @16384; prio @16384+4M; meta @16384+8M
#define WS_RES_OFF   16384
#define WS_PRIO_OFF  (16384 + (size_t)NROWS * 4)
#define WS_META_OFF  (16384 + (size_t)NROWS * 8)
#define WS_NEED      (16384 + (size_t)NROWS * 12)

// ---------------- K1: per-block partial max (no atomics) --------------------
__global__ void __launch_bounds__(256, 8) kmax_part(const float* __restrict__ x,
                                                    float* __restrict__ part) {
    __shared__ float s_m[4];
    const int tid = blockIdx.x * 256 + threadIdx.x;
    const int stride = KMB * 256;
    const float4* x4 = (const float4*)x;
    float m = 0.f;
    #pragma unroll
    for (int k = 0; k < 4; ++k) {
        float4 v = x4[tid + k * stride];
        m = fmaxf(m, fmaxf(fmaxf(fabsf(v.x), fabsf(v.y)), fmaxf(fabsf(v.z), fabsf(v.w))));
    }
    if (tid < (CH4 * OC - 4 * stride)) {
        float4 v = x4[tid + 4 * stride];
        m = fmaxf(m, fmaxf(fmaxf(fabsf(v.x), fabsf(v.y)), fmaxf(fabsf(v.z), fabsf(v.w))));
    }
    #pragma unroll
    for (int off = 32; off > 0; off >>= 1)
        m = fmaxf(m, __shfl_xor(m, off, 64));
    if ((threadIdx.x & 63) == 0) s_m[threadIdx.x >> 6] = m;
    __syncthreads();
    if (threadIdx.x == 0)
        part[blockIdx.x] = fmaxf(fmaxf(s_m[0], s_m[1]), fmaxf(s_m[2], s_m[3]));
}

// ---------------- K2: bulk quant + stage1, metadata out ---------------------
// 4096 blocks x 256 thr, 18.5 KB LDS -> 8 blocks/CU, no serial phases.
// meta pack: gid[13:0] | dir<<14 | (rn+128)<<15
__global__ void __launch_bounds__(256, 8) bulk_kernel(const float* __restrict__ x,
                                                      float* __restrict__ out,
                                                      const float* __restrict__ part,
                                                      float* __restrict__ g_res,
                                                      float* __restrict__ g_pr,
                                                      int* __restrict__ g_me) {
    __shared__ __align__(16) float s_in[BF];
    __shared__ __align__(16) float s_out[BF];
    __shared__ float s_mx[4];

    const int t = threadIdx.x;
    const long long base = (long long)blockIdx.x * BF;

    // coalesced stage-in (576 float4 over 256 thr)
    const float4* x4 = (const float4*)(x + base);
    float4* si4 = (float4*)s_in;
    si4[t] = x4[t];
    si4[t + 256] = x4[t + 256];
    if (t < BF4 - 512) si4[t + 512] = x4[t + 512];

    // scale: exact max over 2048 partials (order-free, fmax exact)
    float m = 0.f;
    #pragma unroll
    for (int k = 0; k < 8; ++k) m = fmaxf(m, part[t + 256 * k]);
    #pragma unroll
    for (int off = 32; off > 0; off >>= 1)
        m = fmaxf(m, __shfl_xor(m, off, 64));
    if ((t & 63) == 0) s_mx[t >> 6] = m;
    __syncthreads();
    float gm = fmaxf(fmaxf(s_mx[0], s_mx[1]), fmaxf(s_mx[2], s_mx[3]));
    const float scale = gm / 127.0f;
    const float iscale = 1.0f / scale;  // mul not div: verified bit-identical (R3-R6 absmax 0.0)

    // ---- stage 1 for row r = blockIdx*256 + t ----
    const int row = blockIdx.x * RPB + t;
    float rn[KK], re[KK];
    float e = 0.f;
    #pragma unroll
    for (int k = 0; k < KK; ++k) {
        float q = s_in[t * KK + k] * iscale;  // stride-9 dwords: 2 lanes/bank, free
        q = fminf(fmaxf(q, -127.f), 127.f);
        float r = rintf(q);                   // round half to even
        rn[k] = r;
        re[k] = r - q;
        e += re[k];
    }
    int nf = (int)rintf(fabsf(e));
    bool up = e < 0.f;
    unsigned flipped = 0u;
    int bidx = -1;
    float b_re = 0.f, b_rn = 0.f;
    for (int f = 0; f < nf; ++f) {
        float bp = 0.f; int bk = -1; float cre = 0.f, crn = 0.f;
        #pragma unroll
        for (int k = 0; k < KK; ++k) {
            bool cand = up ? (re[k] < 0.f) : (re[k] > 0.f);
            float p = (cand && !((flipped >> k) & 1u)) ? fabsf(re[k]) : 0.f;
            if (p > bp) { bp = p; bk = k; cre = re[k]; crn = rn[k]; }  // strict >: lowest idx wins ties
        }
        if (bk < 0) break;  // safety
        flipped |= (1u << bk);
        bidx = bk; b_re = cre; b_rn = crn;
    }
    float sgn = up ? 1.f : -1.f;

    // final values into s_out (own slots, no conflict hazard)
    #pragma unroll
    for (int k = 0; k < KK; ++k)
        s_out[t * KK + k] = (rn[k] + (((flipped >> k) & 1u) ? sgn : 0.f)) * scale;

    // per-row metadata (coalesced dword stores)
    g_res[row] = e + sgn * (float)__popc(flipped);
    if (bidx >= 0) {
        int gid = (row & (ICN - 1)) * KK + bidx;        // channel-local elem idx, <9216
        g_pr[row] = fabsf(b_re + sgn);
        g_me[row] = gid | (up ? (1 << 14) : 0) | ((((int)b_rn) + 128) << 15);
    } else {
        g_pr[row] = 0.f;
        g_me[row] = 0;
    }
    __syncthreads();

    // coalesced stage-out
    const float4* so4 = (const float4*)s_out;
    float4* o4 = (float4*)(out + base);
    o4[t] = so4[t];
    o4[t + 256] = so4[t + 256];
    if (t < BF4 - 512) o4[t + 512] = so4[t + 512];
}

// ---------------- K3: stage-2 patch, one wave per channel -------------------
__global__ void __launch_bounds__(64) patch_kernel(const float* __restrict__ x,
                                                   float* __restrict__ out,
                                                   const float* __restrict__ part,
                                                   const float* __restrict__ g_res,
                                                   const float* __restrict__ g_pr,
                                                   const int* __restrict__ g_me) {
    const int oc = blockIdx.x;
    const int t  = threadIdx.x;
    const int rb = oc * ICN;
    const long long ocbase = (long long)oc * CH;

    // scale (exact max, any order)
    float m = 0.f;
    #pragma unroll
    for (int k = 0; k < 32; ++k) m = fmaxf(m, part[t + 64 * k]);
    #pragma unroll
    for (int off = 32; off > 0; off >>= 1)
        m = fmaxf(m, __shfl_xor(m, off, 64));
    const float scale = m / 127.0f;
    const float iscale = 1.0f / scale;

    // channel residual sum — SAME fp order as R5 (lane-sequential then butterfly)
    float s = 0.f;
    #pragma unroll
    for (int i = 0; i < ICN / 64; ++i) s += g_res[rb + t + i * 64];
    #pragma unroll
    for (int off = 32; off > 0; off >>= 1) s += __shfl_xor(s, off, 64);

    int n2 = (int)rintf(fabsf(s));
    bool up2 = s < 0.f;
    if (n2 == 0) return;

    float p[ICN / 64];
    int   me[ICN / 64];
    #pragma unroll
    for (int i = 0; i < ICN / 64; ++i) {
        int r = rb + t + i * 64;
        float pr = g_pr[r];
        int meta = g_me[r];
        int dir = (meta >> 14) & 1;            // 1: row flipped up -> stage-2 down candidate
        bool match = ((dir != 0) != up2);
        p[i] = (pr > 0.f && match) ? pr : 0.f;
        me[i] = meta;
    }
    int f = 0;
    for (; f < n2; ++f) {
        float bp = 0.f; int brow = ICN; int bmeta = 0;  // ICN loses all index ties
        #pragma unroll
        for (int i = 0; i < ICN / 64; ++i)
            if (p[i] > bp) { bp = p[i]; brow = t + i * 64; bmeta = me[i]; }
        #pragma unroll
        for (int off = 32; off > 0; off >>= 1) {
            float op = __shfl_xor(bp, off, 64);
            int  orow = __shfl_xor(brow, off, 64);
            int  ome  = __shfl_xor(bmeta, off, 64);
            if (op > bp || (op == bp && orow < brow)) { bp = op; brow = orow; bmeta = ome; }
        }
        if (bp <= 0.f) break;  // exhausted -> fallback
        if (t == (brow & 63)) {
            #pragma unroll
            for (int i = 0; i < ICN / 64; ++i)
                if (i == (brow >> 6)) p[i] = 0.f;
        }
        if (t == 0) {
            int gid = bmeta & 0x3FFF;
            float rev = (float)(((bmeta >> 15) & 0xFF) - 128);  // original rn
            out[ocbase + gid] = rev * scale;                    // revert boundary (bit-identical to R5)
        }
    }

    if (f < n2) {  // dead overflow path; deviation <= 1 step
        int remaining = n2 - f;
        if (remaining > CH) remaining = CH;
        for (int j = t; j < remaining; j += 64) {
            float q = x[ocbase + j] * iscale;
            q = fminf(fmaxf(q, -127.f), 127.f);
            float r = rintf(q);
            float rr = r - q;
            float v = up2 ? ((rr < 0.f) ? r + 1.f : r)
                          : ((rr > 0.f) ? r - 1.f : r);
            out[ocbase + j] = v * scale;
        }
    }
}

// ============================================================================
// Fallback (R5, verified exact): monolithic squant
// ============================================================================
#define BT 512
__global__ void __launch_bounds__(BT, 8) squant_kernel(const float* __restrict__ x,
                                                       float* __restrict__ out,
                                                       const float* __restrict__ part) {
    __shared__ __align__(16) unsigned char s_mem[CH * 4];
    __shared__ float s_mx[8];
    float* s_x   = (float*)s_mem;
    short* s_q   = (short*)s_mem;
    float* s_res = (float*)(s_mem + 18432);
    float* s_pr  = (float*)(s_mem + 22528);
    int*   s_me  = (int*)(s_mem + 26624);

    const int oc = blockIdx.x;
    const int t  = threadIdx.x;
    const long long ocbase = (long long)oc * CH;

    const float4* x4 = (const float4*)(x + ocbase);
    float4* s4 = (float4*)s_mem;
    #pragma unroll
    for (int k = 0; k < 4; ++k) s4[t + BT * k] = x4[t + BT * k];
    if (t < CH4 - 4 * BT) s4[4 * BT + t] = x4[4 * BT + t];

    float m = fmaxf(fmaxf(part[t], part[t + BT]),
                    fmaxf(part[t + 2 * BT], part[t + 3 * BT]));
    #pragma unroll
    for (int off = 32; off > 0; off >>= 1)
        m = fmaxf(m, __shfl_xor(m, off, 64));
    if ((t & 63) == 0) s_mx[t >> 6] = m;
    __syncthreads();
    float gm = s_mx[0];
    #pragma unroll
    for (int w = 1; w < 8; ++w) gm = fmaxf(gm, s_mx[w]);
    const float scale = gm / 127.0f;
    const float iscale = 1.0f / scale;

    float rn2[2][KK];
    unsigned flip2[2];
    float res2[2], pr2[2], sg2[2];
    int me2[2];
    #pragma unroll
    for (int half = 0; half < 2; ++half) {
        const int row = t + half * BT;
        float re[KK];
        float e = 0.f;
        #pragma unroll
        for (int k = 0; k < KK; ++k) {
            float q = s_x[row * KK + k] * iscale;
            q = fminf(fmaxf(q, -127.f), 127.f);
            float r = rintf(q);
            rn2[half][k] = r;
            re[k] = r - q;
            e += re[k];
        }
        int nf = (int)rintf(fabsf(e));
        bool up = e < 0.f;
        unsigned flipped = 0u;
        int bidx = -1;
        float b_re = 0.f;
        for (int f = 0; f < nf; ++f) {
            float bp = 0.f; int bk = -1; float cre = 0.f;
            #pragma unroll
            for (int k = 0; k < KK; ++k) {
                bool cand = up ? (re[k] < 0.f) : (re[k] > 0.f);
                float p = (cand && !((flipped >> k) & 1u)) ? fabsf(re[k]) : 0.f;
                if (p > bp) { bp = p; bk = k; cre = re[k]; }
            }
            if (bk < 0) break;
            flipped |= (1u << bk);
            bidx = bk; b_re = cre;
        }
        float sgn = up ? 1.f : -1.f;
        flip2[half] = flipped;
        sg2[half] = sgn;
        res2[half] = e + sgn * (float)__popc(flipped);
        if (bidx >= 0) {
            pr2[half] = fabsf(b_re + sgn);
            me2[half] = (row * KK + bidx) | ((up ? 1 : 0) << 16);
        } else {
            pr2[half] = 0.f;
            me2[half] = 0;
        }
    }
    __syncthreads();

    #pragma unroll
    for (int half = 0; half < 2; ++half) {
        const int row = t + half * BT;
        #pragma unroll
        for (int k = 0; k < KK; ++k)
            s_q[row * KK + k] =
                (short)(int)(rn2[half][k] + (((flip2[half] >> k) & 1u) ? sg2[half] : 0.f));
        s_res[row] = res2[half];
        s_pr[row]  = pr2[half];
        s_me[row]  = me2[half];
    }
    __syncthreads();

    if (t < 64) {
        float s = 0.f;
        #pragma unroll
        for (int i = 0; i < ICN / 64; ++i) s += s_res[t + i * 64];
        #pragma unroll
        for (int off = 32; off > 0; off >>= 1) s += __shfl_xor(s, off, 64);
        int n2 = (int)rintf(fabsf(s));
        bool up2 = s < 0.f;
        if (n2 > 0) {
            float p[ICN / 64];
            #pragma unroll
            for (int i = 0; i < ICN / 64; ++i) {
                int r = t + i * 64;
                float pr = s_pr[r];
                int dir = s_me[r] >> 16;
                bool match = ((dir != 0) != up2);
                p[i] = (pr > 0.f && match) ? pr : 0.f;
            }
            int f = 0;
            for (; f < n2; ++f) {
                float bp = 0.f; int brow = ICN;
                #pragma unroll
                for (int i = 0; i < ICN / 64; ++i)
                    if (p[i] > bp) { bp = p[i]; brow = t + i * 64; }
                #pragma unroll
                for (int off = 32; off > 0; off >>= 1) {
                    float op = __shfl_xor(bp, off, 64);
                    int  orow = __shfl_xor(brow, off, 64);
                    if (op > bp || (op == bp && orow < brow)) { bp = op; brow = orow; }
                }
                if (bp <= 0.f) break;
                if (t == (brow & 63)) {
                    #pragma unroll
                    for (int i = 0; i < ICN / 64; ++i)
                        if (i == (brow >> 6)) p[i] = 0.f;
                }
                if (t == 0) {
                    int meta = s_me[brow];
                    int gid = meta & 0xFFFF;
                    s_q[gid] = (short)(s_q[gid] + ((meta >> 16) ? -1 : 1));
                }
            }
            if (f < n2) {
                int remaining = n2 - f;
                if (remaining > CH) remaining = CH;
                for (int j = t; j < remaining; j += 64) {
                    float q = x[ocbase + j] * iscale;
                    q = fminf(fmaxf(q, -127.f), 127.f);
                    float r = rintf(q);
                    float rr = r - q;
                    float v = up2 ? ((rr < 0.f) ? r + 1.f : r)
                                  : ((rr > 0.f) ? r - 1.f : r);
                    s_q[j] = (short)(int)v;
                }
            }
        }
    }
    __syncthreads();

    const short4* q4 = (const short4*)s_mem;
    float4* o4 = (float4*)(out + ocbase);
    #pragma unroll
    for (int k = 0; k < 4; ++k) {
        short4 v = q4[t + BT * k];
        float4 o;
        o.x = (float)v.x * scale;
        o.y = (float)v.y * scale;
        o.z = (float)v.z * scale;
        o.w = (float)v.w * scale;
        o4[t + BT * k] = o;
    }
    if (t < CH4 - 4 * BT) {
        short4 v = q4[4 * BT + t];
        float4 o;
        o.x = (float)v.x * scale;
        o.y = (float)v.y * scale;
        o.z = (float)v.z * scale;
        o.w = (float)v.w * scale;
        o4[4 * BT + t] = o;
    }
}

extern "C" void kernel_launch(void* const* d_in, const int* in_sizes, int n_in,
                              void* d_out, int out_size, void* d_ws, size_t ws_size,
                              hipStream_t stream) {
    const float* x = (const float*)d_in[0];
    float* out = (float*)d_out;
    float* part = (float*)d_ws;

    kmax_part<<<KMB, 256, 0, stream>>>(x, part);

    if (ws_size >= WS_NEED) {
        float* g_res = (float*)((char*)d_ws + WS_RES_OFF);
        float* g_pr  = (float*)((char*)d_ws + WS_PRIO_OFF);
        int*   g_me  = (int*)((char*)d_ws + WS_META_OFF);
        bulk_kernel<<<BULKB, 256, 0, stream>>>(x, out, part, g_res, g_pr, g_me);
        patch_kernel<<<OC, 64, 0, stream>>>(x, out, part, g_res, g_pr, g_me);
    } else {
        squant_kernel<<<OC, BT, 0, stream>>>(x, out, part);
    }
}